// Round 6
// baseline (150.562 us; speedup 1.0000x reference)
//
#include <hip/hip_runtime.h>

typedef _Float16 f16;
typedef f16 f16x2 __attribute__((ext_vector_type(2)));
typedef f16 f16x4 __attribute__((ext_vector_type(4)));
typedef f16 f16x8 __attribute__((ext_vector_type(8)));
typedef float f32x4 __attribute__((ext_vector_type(4)));

constexpr int Mdim = 32768, Ndim = 1024, Kdim = 1024;
constexpr int BM = 256, BN = 256, BK = 64;
constexpr int NT = Kdim / BK;   // 16 K-steps

static __device__ inline f16x2 cvt2(float a, float b) {
    return __builtin_bit_cast(f16x2, __builtin_amdgcn_cvt_pkrtz(a, b));
}
static __device__ inline f16x4 cvt4(float4 v) {
    f16x2 lo = cvt2(v.x, v.y), hi = cvt2(v.z, v.w);
    return __builtin_shufflevector(lo, hi, 0, 1, 2, 3);
}
// raw barrier: does NOT drain vmcnt -> in-flight global loads survive it.
static __device__ inline void bar() {
    asm volatile("" ::: "memory");
    __builtin_amdgcn_s_barrier();
    asm volatile("" ::: "memory");
}

// out[b,n] = fp32(sum_k fp16(x[b,k]) * fp16(w[n,k])) + bias[n]
// (reference's early-termination mask is always-true: tstat >= 0 > TAU never holds)
//
// m201-style 4-phase/K-step schedule, reg-staged (fp32->fp16 cvt forces it):
// P0{issueA(t+1)|af0,1}MFMA  P1{issueB(t+1)|af2,3}MFMA
// P2{cvtWrA(t+1)|af4,5}MFMA  P3{cvtWrB(t+1)+lgkm0|af6,7}MFMA
// Raw barriers keep reg-loads in flight across phases (counted vmcnt for free).
__global__ __launch_bounds__(512, 2)
void etrow_gemm(const float* __restrict__ X, const float* __restrict__ W,
                const float* __restrict__ bias, float* __restrict__ out)
{
    __shared__ f16 As[2][BM * BK];   // 32 KB per buffer
    __shared__ f16 Bs[2][BN * BK];   // 128 KB total -> 1 block/CU

    // bijective XCD-aware swizzle (512 blocks, 64 per XCD)
    const int bid = blockIdx.x;
    const int cpx = gridDim.x >> 3;
    const int wg  = (bid & 7) * cpx + (bid >> 3);
    const int mIdx = wg >> 2;        // Ndim/BN == 4 n-tiles, n fastest
    const int nIdx = wg & 3;

    const int tid  = threadIdx.x;
    const int lane = tid & 63;
    const int wave = tid >> 6;            // 0..7
    const int wr   = (wave >> 2) * 128;   // 2 m-waves x 4 n-waves, wave tile 128x64
    const int wc   = (wave & 3) * 64;

    const int r0 = tid >> 4;    // 0..31 — staging row within 32-row pass
    const int c4 = tid & 15;    // which float4 of the 64-wide K slab

    const float* Xb = X + (size_t)mIdx * BM * Kdim;
    const float* Wb = W + (size_t)nIdx * BN * Kdim;

    float4 SA[8], SB[8];        // in-flight staging regs (A and B legs)
    f32x4 acc[8][4] = {};

    auto issueA = [&](int kt) {
        const float* p = Xb + kt * BK + c4 * 4;
        #pragma unroll
        for (int q = 0; q < 8; ++q)
            SA[q] = *(const float4*)(p + (q * 32 + r0) * Kdim);
    };
    auto issueB = [&](int kt) {
        const float* p = Wb + kt * BK + c4 * 4;
        #pragma unroll
        for (int q = 0; q < 8; ++q)
            SB[q] = *(const float4*)(p + (q * 32 + r0) * Kdim);
    };
    auto cvtWrA = [&](f16* lds) {
        #pragma unroll
        for (int q = 0; q < 8; ++q) {
            const int r = q * 32 + r0;
            const int byte = (r * 128 + c4 * 8) ^ ((r & 7) << 4);
            *(f16x4*)((char*)lds + byte) = cvt4(SA[q]);
        }
    };
    auto cvtWrB = [&](f16* lds) {
        #pragma unroll
        for (int q = 0; q < 8; ++q) {
            const int r = q * 32 + r0;
            const int byte = (r * 128 + c4 * 8) ^ ((r & 7) << 4);
            *(f16x4*)((char*)lds + byte) = cvt4(SB[q]);
        }
    };

    // one phase: open half {caller's stage op; af reads} / bar / MFMA quad / bar
    auto phase = [&](const f16* Ac, const f16* Bc, int m0) {
        f16x8 af[2][2];
        #pragma unroll
        for (int mi = 0; mi < 2; ++mi)
            #pragma unroll
            for (int s = 0; s < 2; ++s) {
                const int r = wr + (m0 + mi) * 16 + (lane & 15);
                const int byte = (r * 128 + s * 64 + (lane >> 4) * 16) ^ ((r & 7) << 4);
                af[mi][s] = *(const f16x8*)((const char*)Ac + byte);
            }
        bar();
        __builtin_amdgcn_s_setprio(1);
        #pragma unroll
        for (int s = 0; s < 2; ++s) {
            f16x8 bf[4];                    // re-read per substep: saves 16 VGPR
            #pragma unroll
            for (int j = 0; j < 4; ++j) {
                const int r = wc + j * 16 + (lane & 15);
                const int byte = (r * 128 + s * 64 + (lane >> 4) * 16) ^ ((r & 7) << 4);
                bf[j] = *(const f16x8*)((const char*)Bc + byte);
            }
            #pragma unroll
            for (int mi = 0; mi < 2; ++mi)
                #pragma unroll
                for (int j = 0; j < 4; ++j)
                    acc[m0 + mi][j] = __builtin_amdgcn_mfma_f32_16x16x32_f16(
                        af[mi][s], bf[j], acc[m0 + mi][j], 0, 0, 0);
        }
        __builtin_amdgcn_s_setprio(0);
        bar();
    };

    // prologue: stage tile 0 (cold stalls, once)
    issueA(0); cvtWrA(&As[0][0]);
    issueB(0); cvtWrB(&Bs[0][0]);
    asm volatile("s_waitcnt lgkmcnt(0)" ::: "memory");
    bar();

    for (int t = 0; t < NT; ++t) {
        const int cur = t & 1;
        f16* Ac = &As[cur][0];     f16* Bc = &Bs[cur][0];
        f16* An = &As[cur ^ 1][0]; f16* Bn = &Bs[cur ^ 1][0];
        const bool hn = (t + 1) < NT;

        if (hn) issueA(t + 1);           // X leg: consumed 2 phases later
        phase(Ac, Bc, 0);
        if (hn) issueB(t + 1);           // W leg (L2-hot): consumed 2 phases later
        phase(Ac, Bc, 2);
        if (hn) cvtWrA(An);              // counted vmcnt on SA only (auto)
        phase(Ac, Bc, 4);
        if (hn) cvtWrB(Bn);
        asm volatile("s_waitcnt lgkmcnt(0)" ::: "memory");  // publish writes
        phase(Ac, Bc, 6);                // >=1 barrier before next-iter readers
    }

    // epilogue: C/D layout col = lane&15, row = (lane>>4)*4 + reg (m89-verified)
    const int col0  = nIdx * BN + wc + (lane & 15);
    const int rbase = mIdx * BM + wr + (lane >> 4) * 4;
    float bv[4];
    #pragma unroll
    for (int n = 0; n < 4; ++n) bv[n] = bias[col0 + n * 16];

    #pragma unroll
    for (int m = 0; m < 8; ++m) {
        #pragma unroll
        for (int j = 0; j < 4; ++j) {
            const int row = rbase + m * 16 + j;
            float* o = out + (size_t)row * Ndim + col0;
            #pragma unroll
            for (int n = 0; n < 4; ++n)
                o[n * 16] = acc[m][n][j] + bv[n];
        }
    }
}

extern "C" void kernel_launch(void* const* d_in, const int* in_sizes, int n_in,
                              void* d_out, int out_size, void* d_ws, size_t ws_size,
                              hipStream_t stream) {
    const float* X  = (const float*)d_in[0];
    const float* W  = (const float*)d_in[1];
    const float* bs = (const float*)d_in[2];
    float* out = (float*)d_out;
    const int grid = (Mdim / BM) * (Ndim / BN);   // 512 blocks
    etrow_gemm<<<grid, 512, 0, stream>>>(X, W, bs, out);
}

// Round 7
// 98.982 us; speedup vs baseline: 1.5211x; 1.5211x over previous
//
#include <hip/hip_runtime.h>

typedef _Float16 f16;
typedef f16 f16x2 __attribute__((ext_vector_type(2)));
typedef f16 f16x4 __attribute__((ext_vector_type(4)));
typedef f16 f16x8 __attribute__((ext_vector_type(8)));
typedef float f32x4 __attribute__((ext_vector_type(4)));

constexpr int Mdim = 32768, Ndim = 1024, Kdim = 1024;
constexpr int BM = 256, BN = 256, BK = 64;
constexpr int NT = Kdim / BK;   // 16 K-steps

static __device__ inline f16x2 cvt2(float a, float b) {
    return __builtin_bit_cast(f16x2, __builtin_amdgcn_cvt_pkrtz(a, b));
}
static __device__ inline f16x4 cvt4(float4 v) {
    f16x2 lo = cvt2(v.x, v.y), hi = cvt2(v.z, v.w);
    return __builtin_shufflevector(lo, hi, 0, 1, 2, 3);
}
// raw barrier: no vmcnt drain -> in-flight global loads survive it (T4 for reg-staging)
static __device__ inline void bar() {
    asm volatile("" ::: "memory");
    __builtin_amdgcn_s_barrier();
    asm volatile("" ::: "memory");
}

// out[b,n] = fp32(sum_k fp16(x[b,k]) * fp16(w[n,k])) + bias[n]
// (reference's early-termination mask is always-true: tstat >= 0 > TAU never holds)
//
// R5 structure (best so far, 96.7us) with ONE change: __syncthreads -> raw
// s_barrier + lgkmcnt(0). __syncthreads emits s_waitcnt vmcnt(0) which drained
// loadA(t+2) at every K-step barrier, exposing ~700cyc HBM latency each step.
// Raw barrier keeps those loads in flight a full iteration (consumer = cvtWrA
// next iter -> counted vmcnt via reg dependency).
__global__ __launch_bounds__(512, 2)
void etrow_gemm(const float* __restrict__ X, const float* __restrict__ W,
                const float* __restrict__ bias, float* __restrict__ out)
{
    __shared__ f16 As[2][BM * BK];   // 32 KB per buffer
    __shared__ f16 Bs[2][BN * BK];   // 128 KB total -> 1 block/CU

    // bijective XCD-aware swizzle (512 blocks, 64 per XCD)
    const int bid = blockIdx.x;
    const int cpx = gridDim.x >> 3;
    const int wg  = (bid & 7) * cpx + (bid >> 3);
    const int mIdx = wg >> 2;        // Ndim/BN == 4 n-tiles, n fastest
    const int nIdx = wg & 3;

    const int tid  = threadIdx.x;
    const int lane = tid & 63;
    const int wave = tid >> 6;            // 0..7
    const int wr   = (wave >> 2) * 128;   // 2 m-waves x 4 n-waves, wave tile 128x64
    const int wc   = (wave & 3) * 64;

    const int r0 = tid >> 4;    // 0..31 — staging row within 32-row pass
    const int c4 = tid & 15;    // which float4 of the 64-wide K slab

    const float* Xb = X + (size_t)mIdx * BM * Kdim;
    const float* Wb = W + (size_t)nIdx * BN * Kdim;

    float4 S[8];                 // single in-flight fp32 set, time-shared A/B (no spill)
    f32x4 acc[8][4] = {};

    auto loadA = [&](int kt) {
        const float* p = Xb + kt * BK + c4 * 4;
        #pragma unroll
        for (int q = 0; q < 8; ++q)
            S[q] = *(const float4*)(p + (q * 32 + r0) * Kdim);
    };
    auto loadB = [&](int kt) {
        const float* p = Wb + kt * BK + c4 * 4;
        #pragma unroll
        for (int q = 0; q < 8; ++q)
            S[q] = *(const float4*)(p + (q * 32 + r0) * Kdim);
    };
    auto cvtWrite = [&](f16* lds) {   // consume S -> f16 LDS (frees S)
        #pragma unroll
        for (int q = 0; q < 8; ++q) {
            const int r = q * 32 + r0;
            const int byte = (r * 128 + c4 * 8) ^ ((r & 7) << 4);
            *(f16x4*)((char*)lds + byte) = cvt4(S[q]);
        }
    };

    auto computeSub = [&](const f16* Ab, const f16* Bb, int s) {
        f16x8 af[8], bf[4];
        const int kb = s * 64 + (lane >> 4) * 16;   // byte offset in row
        #pragma unroll
        for (int i = 0; i < 8; ++i) {
            const int r = wr + i * 16 + (lane & 15);
            const int byte = (r * 128 + kb) ^ ((r & 7) << 4);
            af[i] = *(const f16x8*)((const char*)Ab + byte);
        }
        #pragma unroll
        for (int j = 0; j < 4; ++j) {
            const int r = wc + j * 16 + (lane & 15);
            const int byte = (r * 128 + kb) ^ ((r & 7) << 4);
            bf[j] = *(const f16x8*)((const char*)Bb + byte);
        }
        #pragma unroll
        for (int i = 0; i < 8; ++i)
            #pragma unroll
            for (int j = 0; j < 4; ++j)
                acc[i][j] = __builtin_amdgcn_mfma_f32_16x16x32_f16(
                    af[i], bf[j], acc[i][j], 0, 0, 0);
    };

    // prologue: tile 0 staged; A(1) in flight across the barrier
    loadA(0); cvtWrite(&As[0][0]);
    loadB(0); cvtWrite(&Bs[0][0]);
    loadA(1);
    asm volatile("s_waitcnt lgkmcnt(0)" ::: "memory");
    bar();

    for (int t = 0; t < NT; ++t) {
        const int cur = t & 1, nxt = cur ^ 1;
        // cvtWrite(A,t+1): consumes S (loads a full iteration old -> counted
        // vmcnt, nearly free); then reuse S for the B leg.
        if (t + 1 < NT) { cvtWrite(&As[nxt][0]); loadB(t + 1); }
        computeSub(&As[cur][0], &Bs[cur][0], 0);   // covers B(t+1) L2 latency
        if (t + 1 < NT) { cvtWrite(&Bs[nxt][0]); }
        if (t + 2 < NT) { loadA(t + 2); }          // X leg: in flight across barrier
        computeSub(&As[cur][0], &Bs[cur][0], 1);
        asm volatile("s_waitcnt lgkmcnt(0)" ::: "memory");  // publish our ds_writes
        bar();                                     // raw: loads stay in flight
    }

    // epilogue: C/D layout col = lane&15, row = (lane>>4)*4 + reg (m89-verified)
    const int col0  = nIdx * BN + wc + (lane & 15);
    const int rbase = mIdx * BM + wr + (lane >> 4) * 4;
    float bv[4];
    #pragma unroll
    for (int n = 0; n < 4; ++n) bv[n] = bias[col0 + n * 16];

    #pragma unroll
    for (int m = 0; m < 8; ++m) {
        #pragma unroll
        for (int j = 0; j < 4; ++j) {
            const int row = rbase + m * 16 + j;
            float* o = out + (size_t)row * Ndim + col0;
            #pragma unroll
            for (int n = 0; n < 4; ++n)
                o[n * 16] = acc[m][n][j] + bv[n];
        }
    }
}

extern "C" void kernel_launch(void* const* d_in, const int* in_sizes, int n_in,
                              void* d_out, int out_size, void* d_ws, size_t ws_size,
                              hipStream_t stream) {
    const float* X  = (const float*)d_in[0];
    const float* W  = (const float*)d_in[1];
    const float* bs = (const float*)d_in[2];
    float* out = (float*)d_out;
    const int grid = (Mdim / BM) * (Ndim / BN);   // 512 blocks
    etrow_gemm<<<grid, 512, 0, stream>>>(X, W, bs, out);
}